// Round 15
// baseline (89.044 us; speedup 1.0000x reference)
//
#include <hip/hip_runtime.h>

// NCC loss, fused single pass. R15 = R14 (78.8us) + two straggler-wave cuts:
//  (a) ISSUE no-rezero: h/w boundary masks are z-invariant, so masked lanes
//      keep their init zeros forever; full zeroing only in the (block-uniform,
//      rare) z-out-of-range branch. Removes ~24 v_mov per ISSUE from the
//      3 BSTW-heavy waves (~14% of their P2 stream).
//  (b) s_setprio(1) around BSTW (wave-uniform bs_on branch -> only waves 0-2):
//      T5 regime now applies (real wave role-diversity: 3 heavy + 1 light).
// Volume [B=2][1][D=160][H=192][W=160] fp32. Window 9^3, zero-padded, /729.
// Tile TH=16 x TW=16, ZC=32 planes/chunk (NSTEP=40 -> 20 supersteps of 2).
// Superstep s (planes 2s,2s+1):
//   P1: C(s): H-axis 9-tap hsum->vsum                      | barrier
//   P2: BSTW(s+1) consume bank -> hsum; ISSUE(s+2) refill; D(s) | barrier
// Hazards (single-buffered): hsum w P2(s)->r P1(s+1): 1 bar; C r -> BSTW w:
// 1 bar (WAR); vsum w P1(s)->r P2(s): 1 bar; D r -> C(s+1) w: 1 bar (WAR).

#define NB 2
#define ND 160
#define NH 192
#define NW 160
#define TH 16
#define TW 16
#define ZC 32
#define NSTEP (ZC + 8)      // 40 planes per chunk
#define NSUP (NSTEP / 2)    // 20 supersteps
#define NITER 27            // 3 blocks of 9 (static ring slots)
#define NGRID 1200          // 120 tiles x 5 zchunks x 2 batches
#define CPX (NGRID / 8)
#define HROWS 25
#define HSTR 20
#define VROWS 17
#define VSTR 24
#define VRSTR (5 * VSTR)    // vsum row stride = 120 words
#define NTH 256

#define HSWZ(r) ((((r) >> 3) & 3) << 2)

__device__ __forceinline__ float4 f4add(float4 a, float4 b) {
    return make_float4(a.x + b.x, a.y + b.y, a.z + b.z, a.w + b.w);
}
__device__ __forceinline__ float4 f4sub(float4 a, float4 b) {
    return make_float4(a.x - b.x, a.y - b.y, a.z - b.z, a.w - b.w);
}

// Publish fence: drain own LDS writes, raw barrier. No vmcnt drain.
__device__ __forceinline__ void barw() {
    asm volatile("s_waitcnt lgkmcnt(0)" ::: "memory");
    __builtin_amdgcn_s_barrier();
    asm volatile("" ::: "memory");
}

__global__ __launch_bounds__(NTH) void ncc_main(
        const float* __restrict__ I, const float* __restrict__ J,
        double* __restrict__ gacc) {
    __shared__ float hsum[2][5][HROWS][HSTR];      // 20.0 KB
    __shared__ float vsum[2][VROWS][5][VSTR];      // 16.3 KB  total 36.3 KB
    __shared__ double wred[4];

    const int tid = threadIdx.x;
    const int tx = tid & 15;
    const int ty = tid >> 4;

    // ---- XCD-aware chunked swizzle (bijective: NGRID % 8 == 0) ----
    const int bid = blockIdx.x;
    const int nid = (bid & 7) * CPX + (bid >> 3);
    const int tile = nid / 10;
    const int rem = nid - tile * 10;
    const int zci = rem >> 1;           // 0..4
    const int bb = rem & 1;
    const int tileW = tile % 10;
    const int tileH = tile / 10;
    const int w0 = tileW * TW;
    const int h0 = tileH * TH;
    const int z0 = zci * ZC;
    const size_t volBase = (size_t)bb * ND * NH * NW;

    // ---- BSTW/ISSUE decode: 192 tasks = 2 planes x 24 rows x 4 col-quads,
    //      all-field fused per lane (12-col window, 4 outputs x 5 fields) ----
    const bool bs_on = (tid < 192);
    const int bpl = (bs_on && tid >= 96) ? 1 : 0;
    const int b2 = bs_on ? (tid - bpl * 96) : 0;
    const int br = b2 >> 2;             // 0..23 halo row
    const int bq = b2 & 3;              // quad: outputs 4bq..4bq+3
    const int bh = h0 - 4 + br;
    const bool h_ok = bs_on && bh >= 0 && bh < NH;
    bool wok[3];
    int goff[3];
#pragma unroll
    for (int kk = 0; kk < 3; ++kk) {
        const int w = w0 - 4 + 4 * bq + 4 * kk;   // window cols 4bq-4..4bq+7
        wok[kk] = (w >= 0) && (w <= NW - 4);
        goff[kk] = bh * NW + w;
    }
    // register bank: 12-col raw window, both fields. Init zeros; lanes with
    // !h_ok/!wok are NEVER loaded (masks are z-invariant) so they keep these
    // zeros for the whole kernel. Full re-zero happens only for z-OOB planes.
    float bI[12], bJ[12];
#pragma unroll
    for (int k = 0; k < 3; ++k) {
        *(float4*)&bI[4 * k] = make_float4(0.f, 0.f, 0.f, 0.f);
        *(float4*)&bJ[4 * k] = make_float4(0.f, 0.f, 0.f, 0.f);
    }

    // ---- C decode: tid 96..255 = 2 planes x (5f x 4 colgrp x 4 strips) ----
    const bool c_on = (tid >= 96);
    const int cix = c_on ? (tid - 96) : 0;   // 0..159
    const int cpl = (cix >= 80) ? 1 : 0;
    const int c2 = cix - cpl * 80;
    const int cf = c2 >> 4;
    const int cstrip = (c2 >> 2) & 3;
    const int ccg = c2 & 3;
    const int cr0 = cstrip << 2;
    const int cc0 = ccg << 2;
    float* cdst = &vsum[cpl][cr0][cf][cc0];

// issue up to 6 global float4 loads for superstep t, plane bpl (no wait).
// NO per-plane re-zero: masked lanes retain init zeros. zok branch is
// (nearly) block-uniform -- diverges only within wave 1 at z edges.
#define ISSUE(t) do {                                                          \
    const int zt_ = z0 - 4 + 2 * (t) + bpl;                                    \
    const size_t zb_ = volBase + (size_t)zt_ * (NH * NW);                      \
    if (zt_ >= 0 && zt_ < ND) {                                                \
        _Pragma("unroll") for (int kk = 0; kk < 3; ++kk) {                     \
            if (h_ok && wok[kk]) {                                             \
                *(float4*)&bI[4 * kk] = *(const float4*)(I + zb_ + goff[kk]);  \
                *(float4*)&bJ[4 * kk] = *(const float4*)(J + zb_ + goff[kk]);  \
            }                                                                  \
        }                                                                      \
    } else if (bs_on) {                                                        \
        _Pragma("unroll") for (int kk = 0; kk < 3; ++kk) {                     \
            *(float4*)&bI[4 * kk] = make_float4(0.f, 0.f, 0.f, 0.f);           \
            *(float4*)&bJ[4 * kk] = make_float4(0.f, 0.f, 0.f, 0.f);           \
        }                                                                      \
    }                                                                          \
} while (0)

// sliding 9-sum over 12-value window -> 4 outputs, write hsum (swizzled cols)
#define BSLIDE(EXPR, F) do {                                                   \
    float s_ = EXPR(0);                                                        \
    _Pragma("unroll") for (int k_ = 1; k_ < 9; ++k_) s_ += EXPR(k_);           \
    float o_[4]; o_[0] = s_;                                                   \
    _Pragma("unroll") for (int j_ = 1; j_ < 4; ++j_) {                         \
        s_ += EXPR(j_ + 8) - EXPR(j_ - 1); o_[j_] = s_; }                      \
    *(float4*)&hsum[bpl][F][br][(4 * bq) ^ HSWZ(br)] = *(float4*)&o_[0];       \
} while (0)
#define E_I(k)  bI[k]
#define E_J(k)  bJ[k]
#define E_I2(k) (bI[k] * bI[k])
#define E_J2(k) (bJ[k] * bJ[k])
#define E_IJ(k) (bI[k] * bJ[k])

// consume bank: products + W-axis sliding sums -> hsum (5 fields, 4 outputs)
// setprio(1) only on the 3 bs_on waves (wave-uniform branch): T5 role-split.
#define BSTW() do { if (bs_on) {                                               \
    __builtin_amdgcn_s_setprio(1);                                             \
    BSLIDE(E_I, 0); BSLIDE(E_J, 1); BSLIDE(E_I2, 2);                           \
    BSLIDE(E_J2, 3); BSLIDE(E_IJ, 4);                                          \
    __builtin_amdgcn_s_setprio(0);                                             \
} } while (0)

// swizzled hsum read: row r, col-quad base cc0
#define CRD(r) (*(const float4*)&hsum[cpl][cf][r][cc0 ^ HSWZ(r)])

// H-axis 9-tap sliding sums: 4-row strip, hsum -> vsum (field-interleaved)
#define DO_C() do { if (c_on) {                                                \
    float4 r0v = CRD(cr0 + 0);                                                 \
    float4 r1v = CRD(cr0 + 1);                                                 \
    float4 r2v = CRD(cr0 + 2);                                                 \
    float4 s4 = f4add(f4add(r0v, r1v), r2v);                                   \
    _Pragma("unroll") for (int k = 3; k < 9; ++k)                              \
        s4 = f4add(s4, CRD(cr0 + k));                                          \
    *(float4*)(cdst + 0 * VRSTR) = s4;                                         \
    s4 = f4sub(f4add(s4, CRD(cr0 +  9)), r0v);                                 \
    *(float4*)(cdst + 1 * VRSTR) = s4;                                         \
    s4 = f4sub(f4add(s4, CRD(cr0 + 10)), r1v);                                 \
    *(float4*)(cdst + 2 * VRSTR) = s4;                                         \
    s4 = f4sub(f4add(s4, CRD(cr0 + 11)), r2v);                                 \
    *(float4*)(cdst + 3 * VRSTR) = s4;                                         \
} } while (0)

// D: z-ring + cc epilogue (algebraically reduced, exact identity)
#define DO_D(PL, SLOT, IDX) do {                                               \
    const float* vbase_ = &vsum[PL][ty][0][tx];                                \
    _Pragma("unroll") for (int f = 0; f < 5; ++f) {                            \
        const float v = vbase_[f * VSTR];                                      \
        acc[f] += v - ring[f][SLOT];                                           \
        ring[f][SLOT] = v;                                                     \
    }                                                                          \
    if ((IDX) >= 8) {                                                          \
        const float Is = acc[0], Js = acc[1];                                  \
        const float I2 = acc[2], J2 = acc[3], IJ = acc[4];                     \
        const float inv = 1.0f / 729.0f;                                       \
        const float uI = Is * inv, uJ = Js * inv;                              \
        const float cross = IJ - uI * Js;                                      \
        const float Iv = I2 - uI * Is;                                         \
        const float Jv = J2 - uJ * Js;                                         \
        partial += cross * cross / (Iv * Jv + 1e-5f);                          \
    }                                                                          \
} while (0)

    float ring[5][9];
    float acc[5];
#pragma unroll
    for (int f = 0; f < 5; ++f) {
        acc[f] = 0.f;
#pragma unroll
        for (int k = 0; k < 9; ++k) ring[f][k] = 0.f;
    }
    float partial = 0.f;

    // ---- prologue: superstep 0 staged into hsum; bank refilled for ss 1 ----
    ISSUE(0);
    BSTW();          // compiler waits vmcnt for ISSUE(0) loads (once)
    ISSUE(1);
    barw();

#pragma unroll 1
    for (int ss = 0; ss < NITER; ss += 9) {
#pragma unroll
        for (int jj = 0; jj < 9; ++jj) {
            const int s = ss + jj;        // (2s+p) % 9 == (2jj+p) % 9: static
            if (s < NSUP) {
                // ---- P1: C(s) ----
                DO_C();
                barw();

                // ---- P2: BSTW(s+1) <- bank ; ISSUE(s+2) -> bank ; D(s) ----
                if (s + 1 < NSUP) BSTW();
                if (s + 2 < NSUP) ISSUE(s + 2);
                DO_D(0, (2 * jj) % 9, 2 * s);
                DO_D(1, (2 * jj + 1) % 9, 2 * s + 1);
                barw();
            }
        }
    }

    // ---------- reduction: wave shfl -> LDS -> one atomic per block ----------
    double dp = (double)partial;
#pragma unroll
    for (int off = 32; off > 0; off >>= 1)
        dp += __shfl_down(dp, off, 64);
    if ((tid & 63) == 0) wred[tid >> 6] = dp;
    __syncthreads();
    if (tid == 0) atomicAdd(gacc, wred[0] + wred[1] + wred[2] + wred[3]);
}

__global__ void ncc_fin(const double* __restrict__ gacc, float* __restrict__ out) {
    out[0] = (float)(-gacc[0] / (double)((long long)NB * ND * NH * NW));
}

extern "C" void kernel_launch(void* const* d_in, const int* in_sizes, int n_in,
                              void* d_out, int out_size, void* d_ws, size_t ws_size,
                              hipStream_t stream) {
    const float* I = (const float*)d_in[0];   // y_true
    const float* J = (const float*)d_in[1];   // y_pred
    double* ws = (double*)d_ws;

    hipMemsetAsync(d_ws, 0, sizeof(double), stream);   // graph-capture safe

    ncc_main<<<dim3(NGRID), NTH, 0, stream>>>(I, J, ws);   // 1D swizzled grid
    ncc_fin<<<1, 1, 0, stream>>>(ws, (float*)d_out);
}

// Round 16
// 85.147 us; speedup vs baseline: 1.0458x; 1.0458x over previous
//
#include <hip/hip_runtime.h>

// NCC loss, fused single pass. R16 = R14 (78.8us best) + ISSUE-no-rezero ONLY.
// (R15 bundled no-rezero + setprio and regressed to 89us; m190 says setprio
// hurts barrier-synced structures -- this round isolates the variables:
// setprio REMOVED, no-rezero KEPT.)
//  - ISSUE no-rezero: h/w boundary masks are z-invariant, so masked lanes keep
//    their init zeros forever; full zeroing only in the (block-uniform, rare)
//    z-out-of-range branch. Removes ~24 v_mov per ISSUE from the BSTW waves.
// Volume [B=2][1][D=160][H=192][W=160] fp32. Window 9^3, zero-padded, /729.
// Tile TH=16 x TW=16, ZC=32 planes/chunk (NSTEP=40 -> 20 supersteps of 2).
// Superstep s (planes 2s,2s+1):
//   P1: C(s): H-axis 9-tap hsum->vsum                      | barrier
//   P2: BSTW(s+1) consume bank -> hsum; ISSUE(s+2) refill; D(s) | barrier
// Hazards (single-buffered): hsum w P2(s)->r P1(s+1): 1 bar; C r -> BSTW w:
// 1 bar (WAR); vsum w P1(s)->r P2(s): 1 bar; D r -> C(s+1) w: 1 bar (WAR).

#define NB 2
#define ND 160
#define NH 192
#define NW 160
#define TH 16
#define TW 16
#define ZC 32
#define NSTEP (ZC + 8)      // 40 planes per chunk
#define NSUP (NSTEP / 2)    // 20 supersteps
#define NITER 27            // 3 blocks of 9 (static ring slots)
#define NGRID 1200          // 120 tiles x 5 zchunks x 2 batches
#define CPX (NGRID / 8)
#define HROWS 25
#define HSTR 20
#define VROWS 17
#define VSTR 24
#define VRSTR (5 * VSTR)    // vsum row stride = 120 words
#define NTH 256

#define HSWZ(r) ((((r) >> 3) & 3) << 2)

__device__ __forceinline__ float4 f4add(float4 a, float4 b) {
    return make_float4(a.x + b.x, a.y + b.y, a.z + b.z, a.w + b.w);
}
__device__ __forceinline__ float4 f4sub(float4 a, float4 b) {
    return make_float4(a.x - b.x, a.y - b.y, a.z - b.z, a.w - b.w);
}

// Publish fence: drain own LDS writes, raw barrier. No vmcnt drain.
__device__ __forceinline__ void barw() {
    asm volatile("s_waitcnt lgkmcnt(0)" ::: "memory");
    __builtin_amdgcn_s_barrier();
    asm volatile("" ::: "memory");
}

__global__ __launch_bounds__(NTH) void ncc_main(
        const float* __restrict__ I, const float* __restrict__ J,
        double* __restrict__ gacc) {
    __shared__ float hsum[2][5][HROWS][HSTR];      // 20.0 KB
    __shared__ float vsum[2][VROWS][5][VSTR];      // 16.3 KB  total 36.3 KB
    __shared__ double wred[4];

    const int tid = threadIdx.x;
    const int tx = tid & 15;
    const int ty = tid >> 4;

    // ---- XCD-aware chunked swizzle (bijective: NGRID % 8 == 0) ----
    const int bid = blockIdx.x;
    const int nid = (bid & 7) * CPX + (bid >> 3);
    const int tile = nid / 10;
    const int rem = nid - tile * 10;
    const int zci = rem >> 1;           // 0..4
    const int bb = rem & 1;
    const int tileW = tile % 10;
    const int tileH = tile / 10;
    const int w0 = tileW * TW;
    const int h0 = tileH * TH;
    const int z0 = zci * ZC;
    const size_t volBase = (size_t)bb * ND * NH * NW;

    // ---- BSTW/ISSUE decode: 192 tasks = 2 planes x 24 rows x 4 col-quads,
    //      all-field fused per lane (12-col window, 4 outputs x 5 fields) ----
    const bool bs_on = (tid < 192);
    const int bpl = (bs_on && tid >= 96) ? 1 : 0;
    const int b2 = bs_on ? (tid - bpl * 96) : 0;
    const int br = b2 >> 2;             // 0..23 halo row
    const int bq = b2 & 3;              // quad: outputs 4bq..4bq+3
    const int bh = h0 - 4 + br;
    const bool h_ok = bs_on && bh >= 0 && bh < NH;
    bool wok[3];
    int goff[3];
#pragma unroll
    for (int kk = 0; kk < 3; ++kk) {
        const int w = w0 - 4 + 4 * bq + 4 * kk;   // window cols 4bq-4..4bq+7
        wok[kk] = (w >= 0) && (w <= NW - 4);
        goff[kk] = bh * NW + w;
    }
    // register bank: 12-col raw window, both fields. Init zeros; lanes with
    // !h_ok/!wok are NEVER loaded (masks are z-invariant) so they keep these
    // zeros for the whole kernel. Full re-zero only for z-OOB planes.
    float bI[12], bJ[12];
#pragma unroll
    for (int k = 0; k < 3; ++k) {
        *(float4*)&bI[4 * k] = make_float4(0.f, 0.f, 0.f, 0.f);
        *(float4*)&bJ[4 * k] = make_float4(0.f, 0.f, 0.f, 0.f);
    }

    // ---- C decode: tid 96..255 = 2 planes x (5f x 4 colgrp x 4 strips) ----
    const bool c_on = (tid >= 96);
    const int cix = c_on ? (tid - 96) : 0;   // 0..159
    const int cpl = (cix >= 80) ? 1 : 0;
    const int c2 = cix - cpl * 80;
    const int cf = c2 >> 4;
    const int cstrip = (c2 >> 2) & 3;
    const int ccg = c2 & 3;
    const int cr0 = cstrip << 2;
    const int cc0 = ccg << 2;
    float* cdst = &vsum[cpl][cr0][cf][cc0];

// issue up to 6 global float4 loads for superstep t, plane bpl (no wait).
// NO per-plane re-zero: masked lanes retain init zeros; z-OOB (block-uniform,
// only at chunk edges) takes the rezero branch.
#define ISSUE(t) do {                                                          \
    const int zt_ = z0 - 4 + 2 * (t) + bpl;                                    \
    const size_t zb_ = volBase + (size_t)zt_ * (NH * NW);                      \
    if (zt_ >= 0 && zt_ < ND) {                                                \
        _Pragma("unroll") for (int kk = 0; kk < 3; ++kk) {                     \
            if (h_ok && wok[kk]) {                                             \
                *(float4*)&bI[4 * kk] = *(const float4*)(I + zb_ + goff[kk]);  \
                *(float4*)&bJ[4 * kk] = *(const float4*)(J + zb_ + goff[kk]);  \
            }                                                                  \
        }                                                                      \
    } else if (bs_on) {                                                        \
        _Pragma("unroll") for (int kk = 0; kk < 3; ++kk) {                     \
            *(float4*)&bI[4 * kk] = make_float4(0.f, 0.f, 0.f, 0.f);           \
            *(float4*)&bJ[4 * kk] = make_float4(0.f, 0.f, 0.f, 0.f);           \
        }                                                                      \
    }                                                                          \
} while (0)

// sliding 9-sum over 12-value window -> 4 outputs, write hsum (swizzled cols)
#define BSLIDE(EXPR, F) do {                                                   \
    float s_ = EXPR(0);                                                        \
    _Pragma("unroll") for (int k_ = 1; k_ < 9; ++k_) s_ += EXPR(k_);           \
    float o_[4]; o_[0] = s_;                                                   \
    _Pragma("unroll") for (int j_ = 1; j_ < 4; ++j_) {                         \
        s_ += EXPR(j_ + 8) - EXPR(j_ - 1); o_[j_] = s_; }                      \
    *(float4*)&hsum[bpl][F][br][(4 * bq) ^ HSWZ(br)] = *(float4*)&o_[0];       \
} while (0)
#define E_I(k)  bI[k]
#define E_J(k)  bJ[k]
#define E_I2(k) (bI[k] * bI[k])
#define E_J2(k) (bJ[k] * bJ[k])
#define E_IJ(k) (bI[k] * bJ[k])

// consume bank: products + W-axis sliding sums -> hsum (5 fields, 4 outputs)
// NOTE: no setprio (R15's A/B showed the bundle regressed; m190 precedent).
#define BSTW() do { if (bs_on) {                                               \
    BSLIDE(E_I, 0); BSLIDE(E_J, 1); BSLIDE(E_I2, 2);                           \
    BSLIDE(E_J2, 3); BSLIDE(E_IJ, 4);                                          \
} } while (0)

// swizzled hsum read: row r, col-quad base cc0
#define CRD(r) (*(const float4*)&hsum[cpl][cf][r][cc0 ^ HSWZ(r)])

// H-axis 9-tap sliding sums: 4-row strip, hsum -> vsum (field-interleaved)
#define DO_C() do { if (c_on) {                                                \
    float4 r0v = CRD(cr0 + 0);                                                 \
    float4 r1v = CRD(cr0 + 1);                                                 \
    float4 r2v = CRD(cr0 + 2);                                                 \
    float4 s4 = f4add(f4add(r0v, r1v), r2v);                                   \
    _Pragma("unroll") for (int k = 3; k < 9; ++k)                              \
        s4 = f4add(s4, CRD(cr0 + k));                                          \
    *(float4*)(cdst + 0 * VRSTR) = s4;                                         \
    s4 = f4sub(f4add(s4, CRD(cr0 +  9)), r0v);                                 \
    *(float4*)(cdst + 1 * VRSTR) = s4;                                         \
    s4 = f4sub(f4add(s4, CRD(cr0 + 10)), r1v);                                 \
    *(float4*)(cdst + 2 * VRSTR) = s4;                                         \
    s4 = f4sub(f4add(s4, CRD(cr0 + 11)), r2v);                                 \
    *(float4*)(cdst + 3 * VRSTR) = s4;                                         \
} } while (0)

// D: z-ring + cc epilogue (algebraically reduced, exact identity)
#define DO_D(PL, SLOT, IDX) do {                                               \
    const float* vbase_ = &vsum[PL][ty][0][tx];                                \
    _Pragma("unroll") for (int f = 0; f < 5; ++f) {                            \
        const float v = vbase_[f * VSTR];                                      \
        acc[f] += v - ring[f][SLOT];                                           \
        ring[f][SLOT] = v;                                                     \
    }                                                                          \
    if ((IDX) >= 8) {                                                          \
        const float Is = acc[0], Js = acc[1];                                  \
        const float I2 = acc[2], J2 = acc[3], IJ = acc[4];                     \
        const float inv = 1.0f / 729.0f;                                       \
        const float uI = Is * inv, uJ = Js * inv;                              \
        const float cross = IJ - uI * Js;                                      \
        const float Iv = I2 - uI * Is;                                         \
        const float Jv = J2 - uJ * Js;                                         \
        partial += cross * cross / (Iv * Jv + 1e-5f);                          \
    }                                                                          \
} while (0)

    float ring[5][9];
    float acc[5];
#pragma unroll
    for (int f = 0; f < 5; ++f) {
        acc[f] = 0.f;
#pragma unroll
        for (int k = 0; k < 9; ++k) ring[f][k] = 0.f;
    }
    float partial = 0.f;

    // ---- prologue: superstep 0 staged into hsum; bank refilled for ss 1 ----
    ISSUE(0);
    BSTW();          // compiler waits vmcnt for ISSUE(0) loads (once)
    ISSUE(1);
    barw();

#pragma unroll 1
    for (int ss = 0; ss < NITER; ss += 9) {
#pragma unroll
        for (int jj = 0; jj < 9; ++jj) {
            const int s = ss + jj;        // (2s+p) % 9 == (2jj+p) % 9: static
            if (s < NSUP) {
                // ---- P1: C(s) ----
                DO_C();
                barw();

                // ---- P2: BSTW(s+1) <- bank ; ISSUE(s+2) -> bank ; D(s) ----
                if (s + 1 < NSUP) BSTW();
                if (s + 2 < NSUP) ISSUE(s + 2);
                DO_D(0, (2 * jj) % 9, 2 * s);
                DO_D(1, (2 * jj + 1) % 9, 2 * s + 1);
                barw();
            }
        }
    }

    // ---------- reduction: wave shfl -> LDS -> one atomic per block ----------
    double dp = (double)partial;
#pragma unroll
    for (int off = 32; off > 0; off >>= 1)
        dp += __shfl_down(dp, off, 64);
    if ((tid & 63) == 0) wred[tid >> 6] = dp;
    __syncthreads();
    if (tid == 0) atomicAdd(gacc, wred[0] + wred[1] + wred[2] + wred[3]);
}

__global__ void ncc_fin(const double* __restrict__ gacc, float* __restrict__ out) {
    out[0] = (float)(-gacc[0] / (double)((long long)NB * ND * NH * NW));
}

extern "C" void kernel_launch(void* const* d_in, const int* in_sizes, int n_in,
                              void* d_out, int out_size, void* d_ws, size_t ws_size,
                              hipStream_t stream) {
    const float* I = (const float*)d_in[0];   // y_true
    const float* J = (const float*)d_in[1];   // y_pred
    double* ws = (double*)d_ws;

    hipMemsetAsync(d_ws, 0, sizeof(double), stream);   // graph-capture safe

    ncc_main<<<dim3(NGRID), NTH, 0, stream>>>(I, J, ws);   // 1D swizzled grid
    ncc_fin<<<1, 1, 0, stream>>>(ws, (float*)d_out);
}

// Round 17
// 78.239 us; speedup vs baseline: 1.1381x; 1.0883x over previous
//
#include <hip/hip_runtime.h>

// NCC loss, fused single pass. R17 = exact revert to R14 (78.8us, session best).
// A/B triangle closed: R15 (no-rezero + setprio) = 89.0; R16 (no-rezero only)
// = 85.1; R14 (rezero, no setprio) = 78.8. Attribution: exec-masked loads into
// long-lived regs (no-rezero) serialize on their own prior value (-6us);
// setprio on barrier-synced waves starves co-resident blocks (-4us). Both out.
//  - BSTW 192 tasks, all-field fused per lane (12-col window -> 5 fields x 4 out)
//  - vsum field-interleaved [2][17][5][24]
//  - XCD-chunked bijective swizzle (FETCH 240->76 MB), hsum XOR swizzle
//  - 2-barrier superstep, lgkmcnt-only fences, consume-then-refill reg prefetch
// Volume [B=2][1][D=160][H=192][W=160] fp32. Window 9^3, zero-padded, /729.
// Tile TH=16 x TW=16, ZC=32 planes/chunk (NSTEP=40 -> 20 supersteps of 2).
// Superstep s (planes 2s,2s+1):
//   P1: C(s): H-axis 9-tap hsum->vsum                      | barrier
//   P2: BSTW(s+1) consume bank -> hsum; ISSUE(s+2) refill; D(s) | barrier
// Hazards (single-buffered): hsum w P2(s)->r P1(s+1): 1 bar; C r -> BSTW w:
// 1 bar (WAR); vsum w P1(s)->r P2(s): 1 bar; D r -> C(s+1) w: 1 bar (WAR).

#define NB 2
#define ND 160
#define NH 192
#define NW 160
#define TH 16
#define TW 16
#define ZC 32
#define NSTEP (ZC + 8)      // 40 planes per chunk
#define NSUP (NSTEP / 2)    // 20 supersteps
#define NITER 27            // 3 blocks of 9 (static ring slots)
#define NGRID 1200          // 120 tiles x 5 zchunks x 2 batches
#define CPX (NGRID / 8)
#define HROWS 25
#define HSTR 20
#define VROWS 17
#define VSTR 24
#define VRSTR (5 * VSTR)    // vsum row stride = 120 words
#define NTH 256

#define HSWZ(r) ((((r) >> 3) & 3) << 2)

__device__ __forceinline__ float4 f4add(float4 a, float4 b) {
    return make_float4(a.x + b.x, a.y + b.y, a.z + b.z, a.w + b.w);
}
__device__ __forceinline__ float4 f4sub(float4 a, float4 b) {
    return make_float4(a.x - b.x, a.y - b.y, a.z - b.z, a.w - b.w);
}

// Publish fence: drain own LDS writes, raw barrier. No vmcnt drain.
__device__ __forceinline__ void barw() {
    asm volatile("s_waitcnt lgkmcnt(0)" ::: "memory");
    __builtin_amdgcn_s_barrier();
    asm volatile("" ::: "memory");
}

__global__ __launch_bounds__(NTH) void ncc_main(
        const float* __restrict__ I, const float* __restrict__ J,
        double* __restrict__ gacc) {
    __shared__ float hsum[2][5][HROWS][HSTR];      // 20.0 KB
    __shared__ float vsum[2][VROWS][5][VSTR];      // 16.3 KB  total 36.3 KB
    __shared__ double wred[4];

    const int tid = threadIdx.x;
    const int tx = tid & 15;
    const int ty = tid >> 4;

    // ---- XCD-aware chunked swizzle (bijective: NGRID % 8 == 0) ----
    const int bid = blockIdx.x;
    const int nid = (bid & 7) * CPX + (bid >> 3);
    const int tile = nid / 10;
    const int rem = nid - tile * 10;
    const int zci = rem >> 1;           // 0..4
    const int bb = rem & 1;
    const int tileW = tile % 10;
    const int tileH = tile / 10;
    const int w0 = tileW * TW;
    const int h0 = tileH * TH;
    const int z0 = zci * ZC;
    const size_t volBase = (size_t)bb * ND * NH * NW;

    // ---- BSTW/ISSUE decode: 192 tasks = 2 planes x 24 rows x 4 col-quads,
    //      ALL-FIELD FUSED per lane (12-col window, 4 outputs x 5 fields) ----
    const bool bs_on = (tid < 192);
    const int bpl = (bs_on && tid >= 96) ? 1 : 0;
    const int b2 = bs_on ? (tid - bpl * 96) : 0;
    const int br = b2 >> 2;             // 0..23 halo row
    const int bq = b2 & 3;              // quad: outputs 4bq..4bq+3
    const int bh = h0 - 4 + br;
    const bool h_ok = bs_on && bh >= 0 && bh < NH;
    bool wok[3];
    int goff[3];
#pragma unroll
    for (int kk = 0; kk < 3; ++kk) {
        const int w = w0 - 4 + 4 * bq + 4 * kk;   // window cols 4bq-4..4bq+7
        wok[kk] = (w >= 0) && (w <= NW - 4);
        goff[kk] = bh * NW + w;
    }
    // register bank: 12-col raw window, both fields (consumed in place)
    float bI[12], bJ[12];
#pragma unroll
    for (int k = 0; k < 3; ++k) {
        *(float4*)&bI[4 * k] = make_float4(0.f, 0.f, 0.f, 0.f);
        *(float4*)&bJ[4 * k] = make_float4(0.f, 0.f, 0.f, 0.f);
    }

    // ---- C decode: tid 96..255 = 2 planes x (5f x 4 colgrp x 4 strips) ----
    const bool c_on = (tid >= 96);
    const int cix = c_on ? (tid - 96) : 0;   // 0..159
    const int cpl = (cix >= 80) ? 1 : 0;
    const int c2 = cix - cpl * 80;
    const int cf = c2 >> 4;
    const int cstrip = (c2 >> 2) & 3;
    const int ccg = c2 & 3;
    const int cr0 = cstrip << 2;
    const int cc0 = ccg << 2;
    float* cdst = &vsum[cpl][cr0][cf][cc0];

// issue 6 global float4 loads (3 I + 3 J) for superstep t, plane bpl (no wait)
// Unconditional re-zero first: destinations are FRESH DEFS every plane, so
// the 6 loads batch-issue with no dependence on prior consumers (R16 lesson).
#define ISSUE(t) do {                                                          \
    const int zt_ = z0 - 4 + 2 * (t) + bpl;                                    \
    const bool zok_ = (zt_ >= 0) && (zt_ < ND);                                \
    const size_t zb_ = volBase + (size_t)zt_ * (NH * NW);                      \
    _Pragma("unroll") for (int kk = 0; kk < 3; ++kk) {                         \
        *(float4*)&bI[4 * kk] = make_float4(0.f, 0.f, 0.f, 0.f);               \
        *(float4*)&bJ[4 * kk] = make_float4(0.f, 0.f, 0.f, 0.f);               \
        if (h_ok && zok_ && wok[kk]) {                                         \
            *(float4*)&bI[4 * kk] = *(const float4*)(I + zb_ + goff[kk]);      \
            *(float4*)&bJ[4 * kk] = *(const float4*)(J + zb_ + goff[kk]);      \
        }                                                                      \
    }                                                                          \
} while (0)

// sliding 9-sum over 12-value window -> 4 outputs, write hsum (swizzled cols)
#define BSLIDE(EXPR, F) do {                                                   \
    float s_ = EXPR(0);                                                        \
    _Pragma("unroll") for (int k_ = 1; k_ < 9; ++k_) s_ += EXPR(k_);           \
    float o_[4]; o_[0] = s_;                                                   \
    _Pragma("unroll") for (int j_ = 1; j_ < 4; ++j_) {                         \
        s_ += EXPR(j_ + 8) - EXPR(j_ - 1); o_[j_] = s_; }                      \
    *(float4*)&hsum[bpl][F][br][(4 * bq) ^ HSWZ(br)] = *(float4*)&o_[0];       \
} while (0)
#define E_I(k)  bI[k]
#define E_J(k)  bJ[k]
#define E_I2(k) (bI[k] * bI[k])
#define E_J2(k) (bJ[k] * bJ[k])
#define E_IJ(k) (bI[k] * bJ[k])

// consume bank: products + W-axis sliding sums -> hsum (5 fields, 4 outputs)
#define BSTW() do { if (bs_on) {                                               \
    BSLIDE(E_I, 0); BSLIDE(E_J, 1); BSLIDE(E_I2, 2);                           \
    BSLIDE(E_J2, 3); BSLIDE(E_IJ, 4);                                          \
} } while (0)

// swizzled hsum read: row r, col-quad base cc0
#define CRD(r) (*(const float4*)&hsum[cpl][cf][r][cc0 ^ HSWZ(r)])

// H-axis 9-tap sliding sums: 4-row strip, hsum -> vsum (field-interleaved)
#define DO_C() do { if (c_on) {                                                \
    float4 r0v = CRD(cr0 + 0);                                                 \
    float4 r1v = CRD(cr0 + 1);                                                 \
    float4 r2v = CRD(cr0 + 2);                                                 \
    float4 s4 = f4add(f4add(r0v, r1v), r2v);                                   \
    _Pragma("unroll") for (int k = 3; k < 9; ++k)                              \
        s4 = f4add(s4, CRD(cr0 + k));                                          \
    *(float4*)(cdst + 0 * VRSTR) = s4;                                         \
    s4 = f4sub(f4add(s4, CRD(cr0 +  9)), r0v);                                 \
    *(float4*)(cdst + 1 * VRSTR) = s4;                                         \
    s4 = f4sub(f4add(s4, CRD(cr0 + 10)), r1v);                                 \
    *(float4*)(cdst + 2 * VRSTR) = s4;                                         \
    s4 = f4sub(f4add(s4, CRD(cr0 + 11)), r2v);                                 \
    *(float4*)(cdst + 3 * VRSTR) = s4;                                         \
} } while (0)

// D: z-ring + cc epilogue (algebraically reduced, exact identity)
#define DO_D(PL, SLOT, IDX) do {                                               \
    const float* vbase_ = &vsum[PL][ty][0][tx];                                \
    _Pragma("unroll") for (int f = 0; f < 5; ++f) {                            \
        const float v = vbase_[f * VSTR];                                      \
        acc[f] += v - ring[f][SLOT];                                           \
        ring[f][SLOT] = v;                                                     \
    }                                                                          \
    if ((IDX) >= 8) {                                                          \
        const float Is = acc[0], Js = acc[1];                                  \
        const float I2 = acc[2], J2 = acc[3], IJ = acc[4];                     \
        const float inv = 1.0f / 729.0f;                                       \
        const float uI = Is * inv, uJ = Js * inv;                              \
        const float cross = IJ - uI * Js;                                      \
        const float Iv = I2 - uI * Is;                                         \
        const float Jv = J2 - uJ * Js;                                         \
        partial += cross * cross / (Iv * Jv + 1e-5f);                          \
    }                                                                          \
} while (0)

    float ring[5][9];
    float acc[5];
#pragma unroll
    for (int f = 0; f < 5; ++f) {
        acc[f] = 0.f;
#pragma unroll
        for (int k = 0; k < 9; ++k) ring[f][k] = 0.f;
    }
    float partial = 0.f;

    // ---- prologue: superstep 0 staged into hsum; bank refilled for ss 1 ----
    ISSUE(0);
    BSTW();          // compiler waits vmcnt for ISSUE(0) loads (once)
    ISSUE(1);
    barw();

#pragma unroll 1
    for (int ss = 0; ss < NITER; ss += 9) {
#pragma unroll
        for (int jj = 0; jj < 9; ++jj) {
            const int s = ss + jj;        // (2s+p) % 9 == (2jj+p) % 9: static
            if (s < NSUP) {
                // ---- P1: C(s) ----
                DO_C();
                barw();

                // ---- P2: BSTW(s+1) <- bank ; ISSUE(s+2) -> bank ; D(s) ----
                if (s + 1 < NSUP) BSTW();
                if (s + 2 < NSUP) ISSUE(s + 2);
                DO_D(0, (2 * jj) % 9, 2 * s);
                DO_D(1, (2 * jj + 1) % 9, 2 * s + 1);
                barw();
            }
        }
    }

    // ---------- reduction: wave shfl -> LDS -> one atomic per block ----------
    double dp = (double)partial;
#pragma unroll
    for (int off = 32; off > 0; off >>= 1)
        dp += __shfl_down(dp, off, 64);
    if ((tid & 63) == 0) wred[tid >> 6] = dp;
    __syncthreads();
    if (tid == 0) atomicAdd(gacc, wred[0] + wred[1] + wred[2] + wred[3]);
}

__global__ void ncc_fin(const double* __restrict__ gacc, float* __restrict__ out) {
    out[0] = (float)(-gacc[0] / (double)((long long)NB * ND * NH * NW));
}

extern "C" void kernel_launch(void* const* d_in, const int* in_sizes, int n_in,
                              void* d_out, int out_size, void* d_ws, size_t ws_size,
                              hipStream_t stream) {
    const float* I = (const float*)d_in[0];   // y_true
    const float* J = (const float*)d_in[1];   // y_pred
    double* ws = (double*)d_ws;

    hipMemsetAsync(d_ws, 0, sizeof(double), stream);   // graph-capture safe

    ncc_main<<<dim3(NGRID), NTH, 0, stream>>>(I, J, ws);   // 1D swizzled grid
    ncc_fin<<<1, 1, 0, stream>>>(ws, (float*)d_out);
}